// Round 7
// baseline (1130.841 us; speedup 1.0000x reference)
//
#include <hip/hip_runtime.h>

// nontemporal int2 load via 8-byte scalar (builtin rejects HIP_vector_type)
__device__ __forceinline__ int2 ld_nt_int2(const int2* p) {
    long long v = __builtin_nontemporal_load((const long long*)p);
    int2 r;
    r.x = (int)(v & 0xffffffffLL);
    r.y = (int)(v >> 32);
    return r;
}

// ---- CSR build -----------------------------------------------------------
__global__ void k_hist(const int* __restrict__ col, int* __restrict__ deg, int E) {
    int e = blockIdx.x * blockDim.x + threadIdx.x;
    if (e < E) atomicAdd(&deg[__builtin_nontemporal_load(&col[e])], 1);
}

// block-level exclusive scan (256 elems / block)
__global__ void k_scan1(const int* __restrict__ deg, int* __restrict__ part,
                        int* __restrict__ bsum, int N) {
    __shared__ int sm[256];
    int t = threadIdx.x;
    int i = blockIdx.x * 256 + t;
    int v = (i < N) ? deg[i] : 0;
    sm[t] = v;
    __syncthreads();
    for (int d = 1; d < 256; d <<= 1) {
        int add = (t >= d) ? sm[t - d] : 0;
        __syncthreads();
        sm[t] += add;
        __syncthreads();
    }
    if (i < N) part[i] = sm[t] - v;  // exclusive
    if (t == 255) bsum[blockIdx.x] = sm[255];
}

__global__ void k_scan2(int* __restrict__ bsum, int nb) {
    __shared__ int sm[512];
    int t = threadIdx.x;
    int v = (t < nb) ? bsum[t] : 0;
    sm[t] = v;
    __syncthreads();
    for (int d = 1; d < 512; d <<= 1) {
        int add = (t >= d) ? sm[t - d] : 0;
        __syncthreads();
        sm[t] += add;
        __syncthreads();
    }
    if (t < nb) bsum[t] = sm[t] - v;  // exclusive block offsets
}

// scan finalize + dinv + y4 (layer-1 pre-agg in 3-dim space), fused
__global__ void k_scan3d(const int* __restrict__ part, const int* __restrict__ bsum,
                         const int* __restrict__ deg, const float* __restrict__ x,
                         int* __restrict__ off, int* __restrict__ cursor,
                         float* __restrict__ dinv, float4* __restrict__ y4, int N, int E) {
    int i = blockIdx.x * 256 + threadIdx.x;
    if (i < N) {
        int o = part[i] + bsum[blockIdx.x];
        off[i] = o;
        cursor[i] = o;
        float d = rsqrtf((float)deg[i] + 1.0f);
        dinv[i] = d;
        y4[i] = make_float4(d * x[i * 3 + 0], d * x[i * 3 + 1], d * x[i * 3 + 2], 0.f);
    }
    if (i == 0) off[N] = E;
}

// LDS-staged, sub-phased fill: chunk (col,row) loaded to LDS once; 8 sub-phases
// per XCD range shrink the active rowlist2 write window to ~0.4MB/XCD so
// partially-filled 64B lines stay in L2 until all 8 entries arrive.
#define FILL_CHUNKS 1024
#define SUBPH 8
__global__ void k_fill_lds(const int* __restrict__ row, const int* __restrict__ col,
                           int* __restrict__ cursor, int2* __restrict__ rowlist2,
                           int E, int N) {
    __shared__ int scol[3200];
    __shared__ int srow[3200];
    int xcd = blockIdx.x & 7;
    int chunk = blockIdx.x >> 3;
    long long c0 = (long long)E * chunk / FILL_CHUNKS;
    long long c1 = (long long)E * (chunk + 1) / FILL_CHUNKS;
    int len = (int)(c1 - c0);
    for (int i = threadIdx.x; i < len; i += blockDim.x) {
        scol[i] = __builtin_nontemporal_load(&col[c0 + i]);
        srow[i] = __builtin_nontemporal_load(&row[c0 + i]);
    }
    __syncthreads();
    for (int p = 0; p < SUBPH; p++) {
        int sr = xcd * SUBPH + p;  // global subrange 0..63
        int lo = (int)((long long)N * sr >> 6);
        int hi = (int)((long long)N * (sr + 1) >> 6);
        for (int i = threadIdx.x; i < len; i += blockDim.x) {
            int c = scol[i];
            if (c >= lo && c < hi) {
                int pp = atomicAdd(&cursor[c], 1);
                rowlist2[pp] = make_int2(srow[i], (int)(c0 + i));
            }
        }
        __syncthreads();  // keep sub-phases aligned -> small write window
    }
}

// ---- fused layer1+lin2: agg3 = y[n]+sum y[r]; h1 = relu(dinv*(agg3@W1)+b1);
//      g2 = dinv * (h1 @ W2). h1 never materialized. ------------------------
__global__ void k_layer12(const float4* __restrict__ y4, const int* __restrict__ off,
                          const int2* __restrict__ rowlist2, const float* __restrict__ dinv,
                          const float* __restrict__ W1, const float* __restrict__ b1,
                          const float* __restrict__ W2, float* __restrict__ g2, int N) {
    __shared__ float W2l[4096];
    __shared__ float W1l[192];
    int tid = threadIdx.x;
    for (int i = tid; i < 4096; i += 256) W2l[i] = W2[i];
    if (tid < 192) W1l[tid] = W1[tid];
    __syncthreads();
    int wave = tid >> 6, lane = tid & 63;
    int n = blockIdx.x * 4 + wave;
    if (n >= N) return;
    int s = off[n], epos = off[n + 1];
    float ax, ay, az;
    {
        float4 self = y4[n];
        ax = (lane == 0) ? self.x : 0.f;
        ay = (lane == 0) ? self.y : 0.f;
        az = (lane == 0) ? self.z : 0.f;
    }
    for (int j = s + lane; j < epos; j += 64) {
        int2 rj = ld_nt_int2(&rowlist2[j]);
        float4 t = y4[rj.x];
        ax += t.x; ay += t.y; az += t.z;
    }
#pragma unroll
    for (int d = 1; d < 64; d <<= 1) {
        ax += __shfl_xor(ax, d);
        ay += __shfl_xor(ay, d);
        az += __shfl_xor(az, d);
    }
    float dn = dinv[n];
    float h1 = fmaxf(fmaf(dn, ax * W1l[lane] + ay * W1l[64 + lane] + az * W1l[128 + lane],
                          b1[lane]), 0.0f);
    float acc2 = 0.f;
#pragma unroll
    for (int k = 0; k < 64; k++) {
        float hk = __shfl(h1, k);
        acc2 = fmaf(hk, W2l[k * 64 + lane], acc2);
    }
    g2[(size_t)n * 64 + lane] = dn * acc2;
}

// ---- FUSED gather2 + edge-MLP precompute: h2 row stays in registers ------
__global__ void k_gather_uv(const float* __restrict__ g, const int* __restrict__ off,
                            const int2* __restrict__ rl, const float* __restrict__ dinv,
                            const float* __restrict__ b2, const float* __restrict__ W3,
                            const float* __restrict__ b3,
                            float* __restrict__ u, float* __restrict__ v, int N) {
    __shared__ float Wa[4096];
    __shared__ float Wb[4096];
    int tid = threadIdx.x;
    for (int i = tid; i < 4096; i += 256) {
        Wa[i] = W3[i];
        Wb[i] = W3[4096 + i];
    }
    __syncthreads();
    int wave = tid >> 6, lane = tid & 63;
    int n = blockIdx.x * 4 + wave;
    if (n >= N) return;
    int s = off[n], epos = off[n + 1];
    float a0 = g[(size_t)n * 64 + lane];  // self loop
    float a1 = 0.f, a2 = 0.f, a3 = 0.f;
    int j = s;
    for (; j + 3 < epos; j += 4) {
        int2 r0 = ld_nt_int2(&rl[j]);
        int2 r1 = ld_nt_int2(&rl[j + 1]);
        int2 r2 = ld_nt_int2(&rl[j + 2]);
        int2 r3 = ld_nt_int2(&rl[j + 3]);
        a0 += g[(size_t)r0.x * 64 + lane];
        a1 += g[(size_t)r1.x * 64 + lane];
        a2 += g[(size_t)r2.x * 64 + lane];
        a3 += g[(size_t)r3.x * 64 + lane];
    }
    for (; j < epos; j++) a1 += g[(size_t)ld_nt_int2(&rl[j]).x * 64 + lane];
    float h2 = fmaxf(fmaf(dinv[n], (a0 + a1) + (a2 + a3), b2[lane]), 0.0f);
    float ua = b3[lane], va = 0.f;
#pragma unroll
    for (int k = 0; k < 64; k++) {
        float hk = __shfl(h2, k);
        ua = fmaf(hk, Wa[k * 64 + lane], ua);
        va = fmaf(hk, Wb[k * 64 + lane], va);
    }
    u[(size_t)n * 64 + lane] = ua;
    v[(size_t)n * 64 + lane] = va;
}

// ---- fallback (unfused) pair, used if ws too small -----------------------
__global__ void k_gather(const float* __restrict__ g, const int* __restrict__ off,
                         const int2* __restrict__ rl, const float* __restrict__ dinv,
                         const float* __restrict__ b, float* __restrict__ h, int N) {
    int tid = threadIdx.x;
    int wave = tid >> 6, lane = tid & 63;
    int n = blockIdx.x * 4 + wave;
    if (n >= N) return;
    int s = off[n], epos = off[n + 1];
    float a0 = g[(size_t)n * 64 + lane];
    float a1 = 0.f, a2 = 0.f, a3 = 0.f;
    int j = s;
    for (; j + 3 < epos; j += 4) {
        int2 r0 = ld_nt_int2(&rl[j]);
        int2 r1 = ld_nt_int2(&rl[j + 1]);
        int2 r2 = ld_nt_int2(&rl[j + 2]);
        int2 r3 = ld_nt_int2(&rl[j + 3]);
        a0 += g[(size_t)r0.x * 64 + lane];
        a1 += g[(size_t)r1.x * 64 + lane];
        a2 += g[(size_t)r2.x * 64 + lane];
        a3 += g[(size_t)r3.x * 64 + lane];
    }
    for (; j < epos; j++) a1 += g[(size_t)ld_nt_int2(&rl[j]).x * 64 + lane];
    h[(size_t)n * 64 + lane] = fmaxf(fmaf(dinv[n], (a0 + a1) + (a2 + a3), b[lane]), 0.0f);
}

__global__ void k_lin3(float* __restrict__ h, const float* __restrict__ W3,
                       const float* __restrict__ b3, float* __restrict__ u, int N) {
    __shared__ float Wa[4096];
    __shared__ float Wb[4096];
    int tid = threadIdx.x;
    for (int i = tid; i < 4096; i += 256) {
        Wa[i] = W3[i];
        Wb[i] = W3[4096 + i];
    }
    __syncthreads();
    int wave = tid >> 6, lane = tid & 63;
    int n = blockIdx.x * 4 + wave;
    if (n >= N) return;
    float hv = h[(size_t)n * 64 + lane];
    float ua = b3[lane], va = 0.f;
#pragma unroll
    for (int k = 0; k < 64; k++) {
        float hk = __shfl(hv, k);
        ua = fmaf(hk, Wa[k * 64 + lane], ua);
        va = fmaf(hk, Wb[k * 64 + lane], va);
    }
    u[(size_t)n * 64 + lane] = ua;
    h[(size_t)n * 64 + lane] = va;
}

// ---- final, CSR order: wave per dst node; v[col] loaded once per node ----
__global__ void k_edge_csr(const float4* __restrict__ u4, const float4* __restrict__ v4,
                           const int* __restrict__ off, const int2* __restrict__ rowlist2,
                           const float4* __restrict__ w44, const float* __restrict__ b4,
                           float* __restrict__ out, int N) {
    int tid = threadIdx.x;
    int wave = tid >> 6, lane = tid & 63;
    int n = blockIdx.x * 4 + wave;
    if (n >= N) return;
    int c16 = lane & 15, grp = lane >> 4;
    int s = off[n], epos = off[n + 1];
    float4 vv = v4[(size_t)n * 16 + c16];   // once per node
    float4 w = w44[c16];
    float bb = b4[0];
    for (int j0 = s; j0 < epos; j0 += 8) {
        int ja = j0 + grp, jb = j0 + 4 + grp;
        bool va_ = ja < epos, vb_ = jb < epos;
        int2 ra = va_ ? ld_nt_int2(&rowlist2[ja]) : make_int2(0, 0);
        int2 rb = vb_ ? ld_nt_int2(&rowlist2[jb]) : make_int2(0, 0);
        float4 a = u4[(size_t)ra.x * 16 + c16];
        float4 b = u4[(size_t)rb.x * 16 + c16];
        float sa = fmaxf(a.x + vv.x, 0.f) * w.x + fmaxf(a.y + vv.y, 0.f) * w.y +
                   fmaxf(a.z + vv.z, 0.f) * w.z + fmaxf(a.w + vv.w, 0.f) * w.w;
        float sb = fmaxf(b.x + vv.x, 0.f) * w.x + fmaxf(b.y + vv.y, 0.f) * w.y +
                   fmaxf(b.z + vv.z, 0.f) * w.z + fmaxf(b.w + vv.w, 0.f) * w.w;
        sa += __shfl_xor(sa, 1); sa += __shfl_xor(sa, 2);
        sa += __shfl_xor(sa, 4); sa += __shfl_xor(sa, 8);
        sb += __shfl_xor(sb, 1); sb += __shfl_xor(sb, 2);
        sb += __shfl_xor(sb, 4); sb += __shfl_xor(sb, 8);
        if (c16 == 0 && va_) __builtin_nontemporal_store(sa + bb, &out[ra.y]);
        if (c16 == 0 && vb_) __builtin_nontemporal_store(sb + bb, &out[rb.y]);
    }
}

extern "C" void kernel_launch(void* const* d_in, const int* in_sizes, int n_in,
                              void* d_out, int out_size, void* d_ws, size_t ws_size,
                              hipStream_t stream) {
    const float* x  = (const float*)d_in[0];
    const int*   ei = (const int*)d_in[1];
    const float* W1 = (const float*)d_in[2];
    const float* b1 = (const float*)d_in[3];
    const float* W2 = (const float*)d_in[4];
    const float* b2 = (const float*)d_in[5];
    const float* W3 = (const float*)d_in[6];
    const float* b3 = (const float*)d_in[7];
    const float* W4 = (const float*)d_in[8];
    const float* b4 = (const float*)d_in[9];
    int N = in_sizes[0] / 3;
    int E = in_sizes[1] / 2;
    const int* row = ei;
    const int* col = ei + E;
    float* out = (float*)d_out;

    char* ws = (char*)d_ws;
    size_t off_b = 0;
    auto alloc = [&](size_t bytes) {
        void* p = ws + off_b;
        off_b += (bytes + 255) & ~(size_t)255;
        return p;
    };
    float* dinv   = (float*)alloc((size_t)N * 4);
    int*   offs   = (int*)alloc((size_t)(N + 1) * 4);
    int*   bsum   = (int*)alloc(512 * 4);
    float* bufA   = (float*)alloc((size_t)N * 64 * 4);   // scratch ints; g2
    float* bufB   = (float*)alloc((size_t)N * 64 * 4);   // y4; then v (or h2/v)
    int2*  rowlist2 = (int2*)alloc((size_t)E * 8);
    size_t base_need = off_b;
    float* bufC = (float*)(ws + base_need);              // u (fused path only)
    bool fused = (base_need + (size_t)N * 64 * 4 <= ws_size);

    // aliases into bufA (all dead before k_layer12 writes g2=bufA):
    int* part   = (int*)bufA;
    int* deg    = (int*)bufA + N;
    int* cursor = (int*)bufA + 2 * N;
    // y4 aliases bufB head (dead before v/h2 written):
    float4* y4 = (float4*)bufB;

    dim3 B(256);
    int nbN     = (N + 255) / 256;
    int nbE     = (E + 255) / 256;
    int nbNode4 = (N + 3) / 4;

    // --- CSR build + normalization ---
    (void)hipMemsetAsync(deg, 0, (size_t)N * 4, stream);
    k_hist<<<nbE, B, 0, stream>>>(col, deg, E);
    k_scan1<<<nbN, B, 0, stream>>>(deg, part, bsum, N);
    k_scan2<<<1, 512, 0, stream>>>(bsum, nbN);
    k_scan3d<<<nbN, B, 0, stream>>>(part, bsum, deg, x, offs, cursor, dinv, y4, N, E);
    k_fill_lds<<<FILL_CHUNKS * 8, B, 0, stream>>>(row, col, cursor, rowlist2, E, N);

    // --- fused layer1 + lin2: writes g2=bufA ---
    k_layer12<<<nbNode4, B, 0, stream>>>(y4, offs, rowlist2, dinv, W1, b1, W2, bufA, N);

    if (fused) {
        // --- gather2 + edge-MLP precompute fused: u=bufC, v=bufB ---
        k_gather_uv<<<nbNode4, B, 0, stream>>>(bufA, offs, rowlist2, dinv, b2, W3, b3,
                                               bufC, bufB, N);
        k_edge_csr<<<nbNode4, B, 0, stream>>>((const float4*)bufC, (const float4*)bufB,
                                              offs, rowlist2, (const float4*)W4, b4, out, N);
    } else {
        // --- fallback: h2=bufB, then u=bufA (over dead g2), v in place ---
        k_gather<<<nbNode4, B, 0, stream>>>(bufA, offs, rowlist2, dinv, b2, bufB, N);
        k_lin3<<<nbNode4, B, 0, stream>>>(bufB, W3, b3, bufA, N);
        k_edge_csr<<<nbNode4, B, 0, stream>>>((const float4*)bufA, (const float4*)bufB,
                                              offs, rowlist2, (const float4*)W4, b4, out, N);
    }
}

// Round 8
// 1052.621 us; speedup vs baseline: 1.0743x; 1.0743x over previous
//
#include <hip/hip_runtime.h>

// nontemporal int2 load via 8-byte scalar (builtin rejects HIP_vector_type)
__device__ __forceinline__ int2 ld_nt_int2(const int2* p) {
    long long v = __builtin_nontemporal_load((const long long*)p);
    int2 r;
    r.x = (int)(v & 0xffffffffLL);
    r.y = (int)(v >> 32);
    return r;
}

// ---- CSR build -----------------------------------------------------------
__global__ void k_hist(const int* __restrict__ col, int* __restrict__ deg, int E) {
    int e = blockIdx.x * blockDim.x + threadIdx.x;
    if (e < E) atomicAdd(&deg[__builtin_nontemporal_load(&col[e])], 1);
}

// block-level exclusive scan (256 elems / block)
__global__ void k_scan1(const int* __restrict__ deg, int* __restrict__ part,
                        int* __restrict__ bsum, int N) {
    __shared__ int sm[256];
    int t = threadIdx.x;
    int i = blockIdx.x * 256 + t;
    int v = (i < N) ? deg[i] : 0;
    sm[t] = v;
    __syncthreads();
    for (int d = 1; d < 256; d <<= 1) {
        int add = (t >= d) ? sm[t - d] : 0;
        __syncthreads();
        sm[t] += add;
        __syncthreads();
    }
    if (i < N) part[i] = sm[t] - v;  // exclusive
    if (t == 255) bsum[blockIdx.x] = sm[255];
}

__global__ void k_scan2(int* __restrict__ bsum, int nb) {
    __shared__ int sm[512];
    int t = threadIdx.x;
    int v = (t < nb) ? bsum[t] : 0;
    sm[t] = v;
    __syncthreads();
    for (int d = 1; d < 512; d <<= 1) {
        int add = (t >= d) ? sm[t - d] : 0;
        __syncthreads();
        sm[t] += add;
        __syncthreads();
    }
    if (t < nb) bsum[t] = sm[t] - v;  // exclusive block offsets
}

// scan finalize + dinv + y4 (layer-1 pre-agg in 3-dim space), fused
__global__ void k_scan3d(const int* __restrict__ part, const int* __restrict__ bsum,
                         const int* __restrict__ deg, const float* __restrict__ x,
                         int* __restrict__ off, int* __restrict__ cursor,
                         float* __restrict__ dinv, float4* __restrict__ y4, int N, int E) {
    int i = blockIdx.x * 256 + threadIdx.x;
    if (i < N) {
        int o = part[i] + bsum[blockIdx.x];
        off[i] = o;
        cursor[i] = o;
        float d = rsqrtf((float)deg[i] + 1.0f);
        dinv[i] = d;
        y4[i] = make_float4(d * x[i * 3 + 0], d * x[i * 3 + 1], d * x[i * 3 + 2], 0.f);
    }
    if (i == 0) off[N] = E;
}

// LDS-staged, sub-phased fill: chunk (col,row) loaded to LDS once; 8 sub-phases
// per XCD range shrink the active rowlist2 write window so partially-filled
// 64B lines stay in L2 until all entries arrive.
#define FILL_CHUNKS 1024
#define SUBPH 8
__global__ void k_fill_lds(const int* __restrict__ row, const int* __restrict__ col,
                           int* __restrict__ cursor, int2* __restrict__ rowlist2,
                           int E, int N) {
    __shared__ int scol[3200];
    __shared__ int srow[3200];
    int xcd = blockIdx.x & 7;
    int chunk = blockIdx.x >> 3;
    long long c0 = (long long)E * chunk / FILL_CHUNKS;
    long long c1 = (long long)E * (chunk + 1) / FILL_CHUNKS;
    int len = (int)(c1 - c0);
    for (int i = threadIdx.x; i < len; i += blockDim.x) {
        scol[i] = __builtin_nontemporal_load(&col[c0 + i]);
        srow[i] = __builtin_nontemporal_load(&row[c0 + i]);
    }
    __syncthreads();
    for (int p = 0; p < SUBPH; p++) {
        int sr = xcd * SUBPH + p;  // global subrange 0..63
        int lo = (int)((long long)N * sr >> 6);
        int hi = (int)((long long)N * (sr + 1) >> 6);
        for (int i = threadIdx.x; i < len; i += blockDim.x) {
            int c = scol[i];
            if (c >= lo && c < hi) {
                int pp = atomicAdd(&cursor[c], 1);
                rowlist2[pp] = make_int2(srow[i], (int)(c0 + i));
            }
        }
        __syncthreads();  // keep sub-phases aligned -> small write window
    }
}

// ---- fused layer1+lin2: agg3 = y[n]+sum y[r]; h1 = relu(dinv*(agg3@W1)+b1);
//      g2 = dinv * (h1 @ W2). h1 never materialized. ------------------------
__global__ void k_layer12(const float4* __restrict__ y4, const int* __restrict__ off,
                          const int2* __restrict__ rowlist2, const float* __restrict__ dinv,
                          const float* __restrict__ W1, const float* __restrict__ b1,
                          const float* __restrict__ W2, float* __restrict__ g2, int N) {
    __shared__ float W2l[4096];
    __shared__ float W1l[192];
    int tid = threadIdx.x;
    for (int i = tid; i < 4096; i += 256) W2l[i] = W2[i];
    if (tid < 192) W1l[tid] = W1[tid];
    __syncthreads();
    int wave = tid >> 6, lane = tid & 63;
    int n = blockIdx.x * 4 + wave;
    if (n >= N) return;
    int s = off[n], epos = off[n + 1];
    float ax, ay, az;
    {
        float4 self = y4[n];
        ax = (lane == 0) ? self.x : 0.f;
        ay = (lane == 0) ? self.y : 0.f;
        az = (lane == 0) ? self.z : 0.f;
    }
    for (int j = s + lane; j < epos; j += 64) {
        int2 rj = ld_nt_int2(&rowlist2[j]);
        float4 t = y4[rj.x];
        ax += t.x; ay += t.y; az += t.z;
    }
#pragma unroll
    for (int d = 1; d < 64; d <<= 1) {
        ax += __shfl_xor(ax, d);
        ay += __shfl_xor(ay, d);
        az += __shfl_xor(az, d);
    }
    float dn = dinv[n];
    float h1 = fmaxf(fmaf(dn, ax * W1l[lane] + ay * W1l[64 + lane] + az * W1l[128 + lane],
                          b1[lane]), 0.0f);
    float acc2 = 0.f;
#pragma unroll
    for (int k = 0; k < 64; k++) {
        float hk = __shfl(h1, k);
        acc2 = fmaf(hk, W2l[k * 64 + lane], acc2);
    }
    g2[(size_t)n * 64 + lane] = dn * acc2;
}

// ---- gather-aggregate (LDS-free, latency-bound -> max occupancy) ---------
__global__ void k_gather(const float* __restrict__ g, const int* __restrict__ off,
                         const int2* __restrict__ rl, const float* __restrict__ dinv,
                         const float* __restrict__ b, float* __restrict__ h, int N) {
    int tid = threadIdx.x;
    int wave = tid >> 6, lane = tid & 63;
    int n = blockIdx.x * 4 + wave;
    if (n >= N) return;
    int s = off[n], epos = off[n + 1];
    float a0 = g[(size_t)n * 64 + lane];
    float a1 = 0.f, a2 = 0.f, a3 = 0.f;
    int j = s;
    for (; j + 3 < epos; j += 4) {
        int2 r0 = ld_nt_int2(&rl[j]);
        int2 r1 = ld_nt_int2(&rl[j + 1]);
        int2 r2 = ld_nt_int2(&rl[j + 2]);
        int2 r3 = ld_nt_int2(&rl[j + 3]);
        a0 += g[(size_t)r0.x * 64 + lane];
        a1 += g[(size_t)r1.x * 64 + lane];
        a2 += g[(size_t)r2.x * 64 + lane];
        a3 += g[(size_t)r3.x * 64 + lane];
    }
    for (; j < epos; j++) a1 += g[(size_t)ld_nt_int2(&rl[j]).x * 64 + lane];
    h[(size_t)n * 64 + lane] = fmaxf(fmaf(dinv[n], (a0 + a1) + (a2 + a3), b[lane]), 0.0f);
}

// ---- edge-MLP precompute: u = h@W3a + b3 (to u), v = h@W3b IN-PLACE ------
__global__ void k_lin3(float* __restrict__ h, const float* __restrict__ W3,
                       const float* __restrict__ b3, float* __restrict__ u, int N) {
    __shared__ float Wa[4096];
    __shared__ float Wb[4096];
    int tid = threadIdx.x;
    for (int i = tid; i < 4096; i += 256) {
        Wa[i] = W3[i];
        Wb[i] = W3[4096 + i];
    }
    __syncthreads();
    int wave = tid >> 6, lane = tid & 63;
    int n = blockIdx.x * 4 + wave;
    if (n >= N) return;
    float hv = h[(size_t)n * 64 + lane];  // full row read before any store
    float ua = b3[lane], va = 0.f;
#pragma unroll
    for (int k = 0; k < 64; k++) {
        float hk = __shfl(hv, k);
        ua = fmaf(hk, Wa[k * 64 + lane], ua);
        va = fmaf(hk, Wb[k * 64 + lane], va);
    }
    u[(size_t)n * 64 + lane] = ua;
    h[(size_t)n * 64 + lane] = va;  // v overwrites h2 in place (wave-local row)
}

// ---- final, CSR order: wave per dst node; v[col] loaded once per node ----
__global__ void k_edge_csr(const float4* __restrict__ u4, const float4* __restrict__ v4,
                           const int* __restrict__ off, const int2* __restrict__ rowlist2,
                           const float4* __restrict__ w44, const float* __restrict__ b4,
                           float* __restrict__ out, int N) {
    int tid = threadIdx.x;
    int wave = tid >> 6, lane = tid & 63;
    int n = blockIdx.x * 4 + wave;
    if (n >= N) return;
    int c16 = lane & 15, grp = lane >> 4;
    int s = off[n], epos = off[n + 1];
    float4 vv = v4[(size_t)n * 16 + c16];   // once per node
    float4 w = w44[c16];
    float bb = b4[0];
    for (int j0 = s; j0 < epos; j0 += 8) {
        int ja = j0 + grp, jb = j0 + 4 + grp;
        bool va_ = ja < epos, vb_ = jb < epos;
        int2 ra = va_ ? ld_nt_int2(&rowlist2[ja]) : make_int2(0, 0);
        int2 rb = vb_ ? ld_nt_int2(&rowlist2[jb]) : make_int2(0, 0);
        float4 a = u4[(size_t)ra.x * 16 + c16];
        float4 b = u4[(size_t)rb.x * 16 + c16];
        float sa = fmaxf(a.x + vv.x, 0.f) * w.x + fmaxf(a.y + vv.y, 0.f) * w.y +
                   fmaxf(a.z + vv.z, 0.f) * w.z + fmaxf(a.w + vv.w, 0.f) * w.w;
        float sb = fmaxf(b.x + vv.x, 0.f) * w.x + fmaxf(b.y + vv.y, 0.f) * w.y +
                   fmaxf(b.z + vv.z, 0.f) * w.z + fmaxf(b.w + vv.w, 0.f) * w.w;
        sa += __shfl_xor(sa, 1); sa += __shfl_xor(sa, 2);
        sa += __shfl_xor(sa, 4); sa += __shfl_xor(sa, 8);
        sb += __shfl_xor(sb, 1); sb += __shfl_xor(sb, 2);
        sb += __shfl_xor(sb, 4); sb += __shfl_xor(sb, 8);
        if (c16 == 0 && va_) __builtin_nontemporal_store(sa + bb, &out[ra.y]);
        if (c16 == 0 && vb_) __builtin_nontemporal_store(sb + bb, &out[rb.y]);
    }
}

extern "C" void kernel_launch(void* const* d_in, const int* in_sizes, int n_in,
                              void* d_out, int out_size, void* d_ws, size_t ws_size,
                              hipStream_t stream) {
    const float* x  = (const float*)d_in[0];
    const int*   ei = (const int*)d_in[1];
    const float* W1 = (const float*)d_in[2];
    const float* b1 = (const float*)d_in[3];
    const float* W2 = (const float*)d_in[4];
    const float* b2 = (const float*)d_in[5];
    const float* W3 = (const float*)d_in[6];
    const float* b3 = (const float*)d_in[7];
    const float* W4 = (const float*)d_in[8];
    const float* b4 = (const float*)d_in[9];
    int N = in_sizes[0] / 3;
    int E = in_sizes[1] / 2;
    const int* row = ei;
    const int* col = ei + E;
    float* out = (float*)d_out;

    char* ws = (char*)d_ws;
    size_t off_b = 0;
    auto alloc = [&](size_t bytes) {
        void* p = ws + off_b;
        off_b += (bytes + 255) & ~(size_t)255;
        return p;
    };
    float* dinv   = (float*)alloc((size_t)N * 4);
    int*   offs   = (int*)alloc((size_t)(N + 1) * 4);
    int*   bsum   = (int*)alloc(512 * 4);
    float* bufA   = (float*)alloc((size_t)N * 64 * 4);   // scratch ints; g2; u
    float* bufB   = (float*)alloc((size_t)N * 64 * 4);   // y4; then h2/v
    int2*  rowlist2 = (int2*)alloc((size_t)E * 8);

    // aliases into bufA (all dead before k_layer12 writes g2=bufA):
    int* part   = (int*)bufA;
    int* deg    = (int*)bufA + N;
    int* cursor = (int*)bufA + 2 * N;
    // y4 aliases bufB head (dead before h2 written):
    float4* y4 = (float4*)bufB;

    dim3 B(256);
    int nbN     = (N + 255) / 256;
    int nbE     = (E + 255) / 256;
    int nbNode4 = (N + 3) / 4;

    // --- CSR build + normalization ---
    (void)hipMemsetAsync(deg, 0, (size_t)N * 4, stream);
    k_hist<<<nbE, B, 0, stream>>>(col, deg, E);
    k_scan1<<<nbN, B, 0, stream>>>(deg, part, bsum, N);
    k_scan2<<<1, 512, 0, stream>>>(bsum, nbN);
    k_scan3d<<<nbN, B, 0, stream>>>(part, bsum, deg, x, offs, cursor, dinv, y4, N, E);
    k_fill_lds<<<FILL_CHUNKS * 8, B, 0, stream>>>(row, col, cursor, rowlist2, E, N);

    // --- fused layer1 + lin2: writes g2=bufA ---
    k_layer12<<<nbNode4, B, 0, stream>>>(y4, offs, rowlist2, dinv, W1, b1, W2, bufA, N);
    // --- layer 2 aggregate: h2=bufB (LDS-free, high occupancy) ---
    k_gather<<<nbNode4, B, 0, stream>>>(bufA, offs, rowlist2, dinv, b2, bufB, N);
    // --- edge MLP precompute: u=bufA (over dead g2), v in place over h2 ---
    k_lin3<<<nbNode4, B, 0, stream>>>(bufB, W3, b3, bufA, N);
    k_edge_csr<<<nbNode4, B, 0, stream>>>((const float4*)bufA, (const float4*)bufB,
                                          offs, rowlist2, (const float4*)W4, b4, out, N);
}

// Round 9
// 796.489 us; speedup vs baseline: 1.4198x; 1.3216x over previous
//
#include <hip/hip_runtime.h>

// ---- CSR build -----------------------------------------------------------
__global__ void k_hist(const int* __restrict__ col, int* __restrict__ deg, int E) {
    int e = blockIdx.x * blockDim.x + threadIdx.x;
    if (e < E) atomicAdd(&deg[__builtin_nontemporal_load(&col[e])], 1);
}

// block-level exclusive scan (256 elems / block)
__global__ void k_scan1(const int* __restrict__ deg, int* __restrict__ part,
                        int* __restrict__ bsum, int N) {
    __shared__ int sm[256];
    int t = threadIdx.x;
    int i = blockIdx.x * 256 + t;
    int v = (i < N) ? deg[i] : 0;
    sm[t] = v;
    __syncthreads();
    for (int d = 1; d < 256; d <<= 1) {
        int add = (t >= d) ? sm[t - d] : 0;
        __syncthreads();
        sm[t] += add;
        __syncthreads();
    }
    if (i < N) part[i] = sm[t] - v;  // exclusive
    if (t == 255) bsum[blockIdx.x] = sm[255];
}

__global__ void k_scan2(int* __restrict__ bsum, int nb) {
    __shared__ int sm[512];
    int t = threadIdx.x;
    int v = (t < nb) ? bsum[t] : 0;
    sm[t] = v;
    __syncthreads();
    for (int d = 1; d < 512; d <<= 1) {
        int add = (t >= d) ? sm[t - d] : 0;
        __syncthreads();
        sm[t] += add;
        __syncthreads();
    }
    if (t < nb) bsum[t] = sm[t] - v;  // exclusive block offsets
}

// scan finalize + dinv + y4 (layer-1 pre-agg in 3-dim space), fused
__global__ void k_scan3d(const int* __restrict__ part, const int* __restrict__ bsum,
                         const int* __restrict__ deg, const float* __restrict__ x,
                         int* __restrict__ off, int* __restrict__ cursor,
                         float* __restrict__ dinv, float4* __restrict__ y4, int N, int E) {
    int i = blockIdx.x * 256 + threadIdx.x;
    if (i < N) {
        int o = part[i] + bsum[blockIdx.x];
        off[i] = o;
        cursor[i] = o;
        float d = rsqrtf((float)deg[i] + 1.0f);
        dinv[i] = d;
        y4[i] = make_float4(d * x[i * 3 + 0], d * x[i * 3 + 1], d * x[i * 3 + 2], 0.f);
    }
    if (i == 0) off[N] = E;
}

// XCD-partitioned fill (blockIdx%8 ~ XCD): rowlist2 writes for node-range r
// come only from one XCD and span ~3.2MB. (Proven 146us; LDS/sub-phase
// variants measured slower -- rounds 6-8.)
__global__ void k_fill_part(const int* __restrict__ row, const int* __restrict__ col,
                            int* __restrict__ cursor, int2* __restrict__ rowlist2,
                            int E, int N) {
    int r = blockIdx.x & 7;
    int chunk = blockIdx.x >> 3;
    int nchunks = gridDim.x >> 3;
    int lo = (int)((long long)N * r >> 3);
    int hi = (int)((long long)N * (r + 1) >> 3);
    long long c0 = (long long)E * chunk / nchunks;
    long long c1 = (long long)E * (chunk + 1) / nchunks;
    for (long long e = c0 + threadIdx.x; e < c1; e += blockDim.x) {
        int c = __builtin_nontemporal_load(&col[e]);
        if (c >= lo && c < hi) {
            int rr = __builtin_nontemporal_load(&row[e]);
            int p = atomicAdd(&cursor[c], 1);
            rowlist2[p] = make_int2(rr, (int)e);
        }
    }
}

// ---- fused layer1+lin2: agg3 = y[n]+sum y[r]; h1 = relu(dinv*(agg3@W1)+b1);
//      g2 = dinv * (h1 @ W2). h1 never materialized. ------------------------
__global__ void k_layer12(const float4* __restrict__ y4, const int* __restrict__ off,
                          const int2* __restrict__ rowlist2, const float* __restrict__ dinv,
                          const float* __restrict__ W1, const float* __restrict__ b1,
                          const float* __restrict__ W2, float* __restrict__ g2, int N) {
    __shared__ float W2l[4096];
    __shared__ float W1l[192];
    int tid = threadIdx.x;
    for (int i = tid; i < 4096; i += 256) W2l[i] = W2[i];
    if (tid < 192) W1l[tid] = W1[tid];
    __syncthreads();
    int wave = tid >> 6, lane = tid & 63;
    int n = blockIdx.x * 4 + wave;
    if (n >= N) return;
    int s = off[n], epos = off[n + 1];
    float ax, ay, az;
    {
        float4 self = y4[n];
        ax = (lane == 0) ? self.x : 0.f;
        ay = (lane == 0) ? self.y : 0.f;
        az = (lane == 0) ? self.z : 0.f;
    }
    for (int j = s + lane; j < epos; j += 64) {
        float4 t = y4[rowlist2[j].x];
        ax += t.x; ay += t.y; az += t.z;
    }
#pragma unroll
    for (int d = 1; d < 64; d <<= 1) {
        ax += __shfl_xor(ax, d);
        ay += __shfl_xor(ay, d);
        az += __shfl_xor(az, d);
    }
    float dn = dinv[n];
    float h1 = fmaxf(fmaf(dn, ax * W1l[lane] + ay * W1l[64 + lane] + az * W1l[128 + lane],
                          b1[lane]), 0.0f);
    float acc2 = 0.f;
#pragma unroll
    for (int k = 0; k < 64; k++) {
        float hk = __shfl(h1, k);
        acc2 = fmaf(hk, W2l[k * 64 + lane], acc2);
    }
    g2[(size_t)n * 64 + lane] = dn * acc2;
}

// ---- gather-aggregate (LDS-free, latency-bound -> 8-deep MLP) ------------
__global__ void k_gather(const float* __restrict__ g, const int* __restrict__ off,
                         const int2* __restrict__ rl, const float* __restrict__ dinv,
                         const float* __restrict__ b, float* __restrict__ h, int N) {
    int tid = threadIdx.x;
    int wave = tid >> 6, lane = tid & 63;
    int n = blockIdx.x * 4 + wave;
    if (n >= N) return;
    int s = off[n], epos = off[n + 1];
    float a0 = g[(size_t)n * 64 + lane];
    float a1 = 0.f, a2 = 0.f, a3 = 0.f;
    float a4 = 0.f, a5 = 0.f, a6 = 0.f, a7 = 0.f;
    int j = s;
    for (; j + 7 < epos; j += 8) {
        int r0 = rl[j].x,     r1 = rl[j + 1].x, r2 = rl[j + 2].x, r3 = rl[j + 3].x;
        int r4 = rl[j + 4].x, r5 = rl[j + 5].x, r6 = rl[j + 6].x, r7 = rl[j + 7].x;
        a0 += g[(size_t)r0 * 64 + lane];
        a1 += g[(size_t)r1 * 64 + lane];
        a2 += g[(size_t)r2 * 64 + lane];
        a3 += g[(size_t)r3 * 64 + lane];
        a4 += g[(size_t)r4 * 64 + lane];
        a5 += g[(size_t)r5 * 64 + lane];
        a6 += g[(size_t)r6 * 64 + lane];
        a7 += g[(size_t)r7 * 64 + lane];
    }
    for (; j < epos; j++) a1 += g[(size_t)rl[j].x * 64 + lane];
    float acc = ((a0 + a1) + (a2 + a3)) + ((a4 + a5) + (a6 + a7));
    h[(size_t)n * 64 + lane] = fmaxf(fmaf(dinv[n], acc, b[lane]), 0.0f);
}

// ---- edge-MLP precompute: u = h@W3a + b3 (to u), v = h@W3b IN-PLACE ------
__global__ void k_lin3(float* __restrict__ h, const float* __restrict__ W3,
                       const float* __restrict__ b3, float* __restrict__ u, int N) {
    __shared__ float Wa[4096];
    __shared__ float Wb[4096];
    int tid = threadIdx.x;
    for (int i = tid; i < 4096; i += 256) {
        Wa[i] = W3[i];
        Wb[i] = W3[4096 + i];
    }
    __syncthreads();
    int wave = tid >> 6, lane = tid & 63;
    int n = blockIdx.x * 4 + wave;
    if (n >= N) return;
    float hv = h[(size_t)n * 64 + lane];  // full row read before any store
    float ua = b3[lane], va = 0.f;
#pragma unroll
    for (int k = 0; k < 64; k++) {
        float hk = __shfl(hv, k);
        ua = fmaf(hk, Wa[k * 64 + lane], ua);
        va = fmaf(hk, Wb[k * 64 + lane], va);
    }
    u[(size_t)n * 64 + lane] = ua;
    h[(size_t)n * 64 + lane] = va;  // v overwrites h2 in place (wave-local row)
}

// ---- final, CSR order: wave per dst node; v[col] loaded once per node;
//      16 edges in flight per wave iteration ------------------------------
__global__ void k_edge_csr(const float4* __restrict__ u4, const float4* __restrict__ v4,
                           const int* __restrict__ off, const int2* __restrict__ rowlist2,
                           const float4* __restrict__ w44, const float* __restrict__ b4,
                           float* __restrict__ out, int N) {
    int tid = threadIdx.x;
    int wave = tid >> 6, lane = tid & 63;
    int n = blockIdx.x * 4 + wave;
    if (n >= N) return;
    int c16 = lane & 15, grp = lane >> 4;
    int s = off[n], epos = off[n + 1];
    float4 vv = v4[(size_t)n * 16 + c16];   // once per node
    float4 w = w44[c16];
    float bb = b4[0];
    for (int j0 = s; j0 < epos; j0 += 16) {
        int ja = j0 + grp, jb = j0 + 4 + grp, jc = j0 + 8 + grp, jd = j0 + 12 + grp;
        bool va_ = ja < epos, vb_ = jb < epos, vc_ = jc < epos, vd_ = jd < epos;
        int2 ra = va_ ? rowlist2[ja] : make_int2(0, 0);
        int2 rb = vb_ ? rowlist2[jb] : make_int2(0, 0);
        int2 rc = vc_ ? rowlist2[jc] : make_int2(0, 0);
        int2 rd = vd_ ? rowlist2[jd] : make_int2(0, 0);
        float4 a = u4[(size_t)ra.x * 16 + c16];
        float4 b = u4[(size_t)rb.x * 16 + c16];
        float4 c = u4[(size_t)rc.x * 16 + c16];
        float4 d = u4[(size_t)rd.x * 16 + c16];
        float sa = fmaxf(a.x + vv.x, 0.f) * w.x + fmaxf(a.y + vv.y, 0.f) * w.y +
                   fmaxf(a.z + vv.z, 0.f) * w.z + fmaxf(a.w + vv.w, 0.f) * w.w;
        float sb = fmaxf(b.x + vv.x, 0.f) * w.x + fmaxf(b.y + vv.y, 0.f) * w.y +
                   fmaxf(b.z + vv.z, 0.f) * w.z + fmaxf(b.w + vv.w, 0.f) * w.w;
        float sc = fmaxf(c.x + vv.x, 0.f) * w.x + fmaxf(c.y + vv.y, 0.f) * w.y +
                   fmaxf(c.z + vv.z, 0.f) * w.z + fmaxf(c.w + vv.w, 0.f) * w.w;
        float sd = fmaxf(d.x + vv.x, 0.f) * w.x + fmaxf(d.y + vv.y, 0.f) * w.y +
                   fmaxf(d.z + vv.z, 0.f) * w.z + fmaxf(d.w + vv.w, 0.f) * w.w;
        sa += __shfl_xor(sa, 1); sa += __shfl_xor(sa, 2);
        sa += __shfl_xor(sa, 4); sa += __shfl_xor(sa, 8);
        sb += __shfl_xor(sb, 1); sb += __shfl_xor(sb, 2);
        sb += __shfl_xor(sb, 4); sb += __shfl_xor(sb, 8);
        sc += __shfl_xor(sc, 1); sc += __shfl_xor(sc, 2);
        sc += __shfl_xor(sc, 4); sc += __shfl_xor(sc, 8);
        sd += __shfl_xor(sd, 1); sd += __shfl_xor(sd, 2);
        sd += __shfl_xor(sd, 4); sd += __shfl_xor(sd, 8);
        if (c16 == 0) {
            if (va_) out[ra.y] = sa + bb;
            if (vb_) out[rb.y] = sb + bb;
            if (vc_) out[rc.y] = sc + bb;
            if (vd_) out[rd.y] = sd + bb;
        }
    }
}

extern "C" void kernel_launch(void* const* d_in, const int* in_sizes, int n_in,
                              void* d_out, int out_size, void* d_ws, size_t ws_size,
                              hipStream_t stream) {
    const float* x  = (const float*)d_in[0];
    const int*   ei = (const int*)d_in[1];
    const float* W1 = (const float*)d_in[2];
    const float* b1 = (const float*)d_in[3];
    const float* W2 = (const float*)d_in[4];
    const float* b2 = (const float*)d_in[5];
    const float* W3 = (const float*)d_in[6];
    const float* b3 = (const float*)d_in[7];
    const float* W4 = (const float*)d_in[8];
    const float* b4 = (const float*)d_in[9];
    int N = in_sizes[0] / 3;
    int E = in_sizes[1] / 2;
    const int* row = ei;
    const int* col = ei + E;
    float* out = (float*)d_out;

    char* ws = (char*)d_ws;
    size_t off_b = 0;
    auto alloc = [&](size_t bytes) {
        void* p = ws + off_b;
        off_b += (bytes + 255) & ~(size_t)255;
        return p;
    };
    float* dinv   = (float*)alloc((size_t)N * 4);
    int*   offs   = (int*)alloc((size_t)(N + 1) * 4);
    int*   bsum   = (int*)alloc(512 * 4);
    float* bufA   = (float*)alloc((size_t)N * 64 * 4);   // scratch ints; g2; u
    float* bufB   = (float*)alloc((size_t)N * 64 * 4);   // y4; then h2/v
    int2*  rowlist2 = (int2*)alloc((size_t)E * 8);

    // aliases into bufA (all dead before k_layer12 writes g2=bufA):
    int* part   = (int*)bufA;
    int* deg    = (int*)bufA + N;
    int* cursor = (int*)bufA + 2 * N;
    // y4 aliases bufB head (dead before h2 written):
    float4* y4 = (float4*)bufB;

    dim3 B(256);
    int nbN     = (N + 255) / 256;
    int nbE     = (E + 255) / 256;
    int nbNode4 = (N + 3) / 4;

    // --- CSR build + normalization ---
    (void)hipMemsetAsync(deg, 0, (size_t)N * 4, stream);
    k_hist<<<nbE, B, 0, stream>>>(col, deg, E);
    k_scan1<<<nbN, B, 0, stream>>>(deg, part, bsum, N);
    k_scan2<<<1, 512, 0, stream>>>(bsum, nbN);
    k_scan3d<<<nbN, B, 0, stream>>>(part, bsum, deg, x, offs, cursor, dinv, y4, N, E);
    k_fill_part<<<2048, B, 0, stream>>>(row, col, cursor, rowlist2, E, N);

    // --- fused layer1 + lin2: writes g2=bufA ---
    k_layer12<<<nbNode4, B, 0, stream>>>(y4, offs, rowlist2, dinv, W1, b1, W2, bufA, N);
    // --- layer 2 aggregate: h2=bufB (LDS-free, high occupancy) ---
    k_gather<<<nbNode4, B, 0, stream>>>(bufA, offs, rowlist2, dinv, b2, bufB, N);
    // --- edge MLP precompute: u=bufA (over dead g2), v in place over h2 ---
    k_lin3<<<nbNode4, B, 0, stream>>>(bufB, W3, b3, bufA, N);
    k_edge_csr<<<nbNode4, B, 0, stream>>>((const float4*)bufA, (const float4*)bufB,
                                          offs, rowlist2, (const float4*)W4, b4, out, N);
}

// Round 10
// 753.468 us; speedup vs baseline: 1.5008x; 1.0571x over previous
//
#include <hip/hip_runtime.h>

// ---- hist + rank: rank[e] = ordinal of edge within its col bucket --------
__global__ void k_histr(const int* __restrict__ col, int* __restrict__ deg,
                        int* __restrict__ rank, int E) {
    int e = blockIdx.x * blockDim.x + threadIdx.x;
    if (e < E) rank[e] = atomicAdd(&deg[col[e]], 1);
}

// block-level exclusive scan (256 elems / block)
__global__ void k_scan1(const int* __restrict__ deg, int* __restrict__ part,
                        int* __restrict__ bsum, int N) {
    __shared__ int sm[256];
    int t = threadIdx.x;
    int i = blockIdx.x * 256 + t;
    int v = (i < N) ? deg[i] : 0;
    sm[t] = v;
    __syncthreads();
    for (int d = 1; d < 256; d <<= 1) {
        int add = (t >= d) ? sm[t - d] : 0;
        __syncthreads();
        sm[t] += add;
        __syncthreads();
    }
    if (i < N) part[i] = sm[t] - v;  // exclusive
    if (t == 255) bsum[blockIdx.x] = sm[255];
}

__global__ void k_scan2(int* __restrict__ bsum, int nb) {
    __shared__ int sm[512];
    int t = threadIdx.x;
    int v = (t < nb) ? bsum[t] : 0;
    sm[t] = v;
    __syncthreads();
    for (int d = 1; d < 512; d <<= 1) {
        int add = (t >= d) ? sm[t - d] : 0;
        __syncthreads();
        sm[t] += add;
        __syncthreads();
    }
    if (t < nb) bsum[t] = sm[t] - v;  // exclusive block offsets
}

// scan finalize + dinv + y4 (layer-1 pre-agg in 3-dim space), fused
__global__ void k_scan3d(const int* __restrict__ part, const int* __restrict__ bsum,
                         const int* __restrict__ deg, const float* __restrict__ x,
                         int* __restrict__ off, float* __restrict__ dinv,
                         float4* __restrict__ y4, int N, int E) {
    int i = blockIdx.x * 256 + threadIdx.x;
    if (i < N) {
        int o = part[i] + bsum[blockIdx.x];
        off[i] = o;
        float d = rsqrtf((float)deg[i] + 1.0f);
        dinv[i] = d;
        y4[i] = make_float4(d * x[i * 3 + 0], d * x[i * 3 + 1], d * x[i * 3 + 2], 0.f);
    }
    if (i == 0) off[N] = E;
}

// pos[e] = CSR slot of edge e (atomic-free; rank captured during hist)
__global__ void k_pos(const int* __restrict__ col, const int* __restrict__ rank,
                      const int* __restrict__ off, int* __restrict__ pos, int E) {
    int e = blockIdx.x * blockDim.x + threadIdx.x;
    if (e < E) pos[e] = off[col[e]] + rank[e];
}

// atomic-free XCD-partitioned scatter: rowlist[pos[e]] = row[e].
// Range test on pos itself (p-space partition), 4B entries.
__global__ void k_fillr(const int* __restrict__ row, const int* __restrict__ pos,
                        int* __restrict__ rowlist, int E) {
    int r = blockIdx.x & 7;
    int chunk = blockIdx.x >> 3;
    int nchunks = gridDim.x >> 3;
    int plo = (int)((long long)E * r >> 3);
    int phi = (int)((long long)E * (r + 1) >> 3);
    long long c0 = (long long)E * chunk / nchunks;
    long long c1 = (long long)E * (chunk + 1) / nchunks;
    for (long long e = c0 + threadIdx.x; e < c1; e += blockDim.x) {
        int p = __builtin_nontemporal_load(&pos[e]);
        if (p >= plo && p < phi)
            rowlist[p] = __builtin_nontemporal_load(&row[e]);
    }
}

// ---- fused layer1+lin2: agg3 = y[n]+sum y[r]; h1 = relu(dinv*(agg3@W1)+b1);
//      g2 = dinv * (h1 @ W2). h1 never materialized. ------------------------
__global__ void k_layer12(const float4* __restrict__ y4, const int* __restrict__ off,
                          const int* __restrict__ rowlist, const float* __restrict__ dinv,
                          const float* __restrict__ W1, const float* __restrict__ b1,
                          const float* __restrict__ W2, float* __restrict__ g2, int N) {
    __shared__ float W2l[4096];
    __shared__ float W1l[192];
    int tid = threadIdx.x;
    for (int i = tid; i < 4096; i += 256) W2l[i] = W2[i];
    if (tid < 192) W1l[tid] = W1[tid];
    __syncthreads();
    int wave = tid >> 6, lane = tid & 63;
    int n = blockIdx.x * 4 + wave;
    if (n >= N) return;
    int s = off[n], epos = off[n + 1];
    float ax, ay, az;
    {
        float4 self = y4[n];
        ax = (lane == 0) ? self.x : 0.f;
        ay = (lane == 0) ? self.y : 0.f;
        az = (lane == 0) ? self.z : 0.f;
    }
    for (int j = s + lane; j < epos; j += 64) {
        float4 t = y4[rowlist[j]];
        ax += t.x; ay += t.y; az += t.z;
    }
#pragma unroll
    for (int d = 1; d < 64; d <<= 1) {
        ax += __shfl_xor(ax, d);
        ay += __shfl_xor(ay, d);
        az += __shfl_xor(az, d);
    }
    float dn = dinv[n];
    float h1 = fmaxf(fmaf(dn, ax * W1l[lane] + ay * W1l[64 + lane] + az * W1l[128 + lane],
                          b1[lane]), 0.0f);
    float acc2 = 0.f;
#pragma unroll
    for (int k = 0; k < 64; k++) {
        float hk = __shfl(h1, k);
        acc2 = fmaf(hk, W2l[k * 64 + lane], acc2);
    }
    g2[(size_t)n * 64 + lane] = dn * acc2;
}

// ---- gather-aggregate (LDS-free, latency-bound -> 8-deep MLP) ------------
__global__ void k_gather(const float* __restrict__ g, const int* __restrict__ off,
                         const int* __restrict__ rl, const float* __restrict__ dinv,
                         const float* __restrict__ b, float* __restrict__ h, int N) {
    int tid = threadIdx.x;
    int wave = tid >> 6, lane = tid & 63;
    int n = blockIdx.x * 4 + wave;
    if (n >= N) return;
    int s = off[n], epos = off[n + 1];
    float a0 = g[(size_t)n * 64 + lane];
    float a1 = 0.f, a2 = 0.f, a3 = 0.f;
    float a4 = 0.f, a5 = 0.f, a6 = 0.f, a7 = 0.f;
    int j = s;
    for (; j + 7 < epos; j += 8) {
        int r0 = rl[j],     r1 = rl[j + 1], r2 = rl[j + 2], r3 = rl[j + 3];
        int r4 = rl[j + 4], r5 = rl[j + 5], r6 = rl[j + 6], r7 = rl[j + 7];
        a0 += g[(size_t)r0 * 64 + lane];
        a1 += g[(size_t)r1 * 64 + lane];
        a2 += g[(size_t)r2 * 64 + lane];
        a3 += g[(size_t)r3 * 64 + lane];
        a4 += g[(size_t)r4 * 64 + lane];
        a5 += g[(size_t)r5 * 64 + lane];
        a6 += g[(size_t)r6 * 64 + lane];
        a7 += g[(size_t)r7 * 64 + lane];
    }
    for (; j < epos; j++) a1 += g[(size_t)rl[j] * 64 + lane];
    float acc = ((a0 + a1) + (a2 + a3)) + ((a4 + a5) + (a6 + a7));
    h[(size_t)n * 64 + lane] = fmaxf(fmaf(dinv[n], acc, b[lane]), 0.0f);
}

// ---- edge-MLP precompute: u = h@W3a + b3 (to u), v = h@W3b IN-PLACE ------
__global__ void k_lin3(float* __restrict__ h, const float* __restrict__ W3,
                       const float* __restrict__ b3, float* __restrict__ u, int N) {
    __shared__ float Wa[4096];
    __shared__ float Wb[4096];
    int tid = threadIdx.x;
    for (int i = tid; i < 4096; i += 256) {
        Wa[i] = W3[i];
        Wb[i] = W3[4096 + i];
    }
    __syncthreads();
    int wave = tid >> 6, lane = tid & 63;
    int n = blockIdx.x * 4 + wave;
    if (n >= N) return;
    float hv = h[(size_t)n * 64 + lane];  // full row read before any store
    float ua = b3[lane], va = 0.f;
#pragma unroll
    for (int k = 0; k < 64; k++) {
        float hk = __shfl(hv, k);
        ua = fmaf(hk, Wa[k * 64 + lane], ua);
        va = fmaf(hk, Wb[k * 64 + lane], va);
    }
    u[(size_t)n * 64 + lane] = ua;
    h[(size_t)n * 64 + lane] = va;  // v overwrites h2 in place (wave-local row)
}

// ---- edge scorer, CSR order, SEQUENTIAL writes to tmp --------------------
__global__ void k_edge_csr(const float4* __restrict__ u4, const float4* __restrict__ v4,
                           const int* __restrict__ off, const int* __restrict__ rowlist,
                           const float4* __restrict__ w44, const float* __restrict__ b4,
                           float* __restrict__ tmp, int N) {
    int tid = threadIdx.x;
    int wave = tid >> 6, lane = tid & 63;
    int n = blockIdx.x * 4 + wave;
    if (n >= N) return;
    int c16 = lane & 15, grp = lane >> 4;
    int s = off[n], epos = off[n + 1];
    float4 vv = v4[(size_t)n * 16 + c16];   // once per node
    float4 w = w44[c16];
    float bb = b4[0];
    for (int j0 = s; j0 < epos; j0 += 16) {
        int ja = j0 + grp, jb = j0 + 4 + grp, jc = j0 + 8 + grp, jd = j0 + 12 + grp;
        bool va_ = ja < epos, vb_ = jb < epos, vc_ = jc < epos, vd_ = jd < epos;
        int ra = va_ ? rowlist[ja] : 0;
        int rb = vb_ ? rowlist[jb] : 0;
        int rc = vc_ ? rowlist[jc] : 0;
        int rd = vd_ ? rowlist[jd] : 0;
        float4 a = u4[(size_t)ra * 16 + c16];
        float4 b = u4[(size_t)rb * 16 + c16];
        float4 c = u4[(size_t)rc * 16 + c16];
        float4 d = u4[(size_t)rd * 16 + c16];
        float sa = fmaxf(a.x + vv.x, 0.f) * w.x + fmaxf(a.y + vv.y, 0.f) * w.y +
                   fmaxf(a.z + vv.z, 0.f) * w.z + fmaxf(a.w + vv.w, 0.f) * w.w;
        float sb = fmaxf(b.x + vv.x, 0.f) * w.x + fmaxf(b.y + vv.y, 0.f) * w.y +
                   fmaxf(b.z + vv.z, 0.f) * w.z + fmaxf(b.w + vv.w, 0.f) * w.w;
        float sc = fmaxf(c.x + vv.x, 0.f) * w.x + fmaxf(c.y + vv.y, 0.f) * w.y +
                   fmaxf(c.z + vv.z, 0.f) * w.z + fmaxf(c.w + vv.w, 0.f) * w.w;
        float sd = fmaxf(d.x + vv.x, 0.f) * w.x + fmaxf(d.y + vv.y, 0.f) * w.y +
                   fmaxf(d.z + vv.z, 0.f) * w.z + fmaxf(d.w + vv.w, 0.f) * w.w;
        sa += __shfl_xor(sa, 1); sa += __shfl_xor(sa, 2);
        sa += __shfl_xor(sa, 4); sa += __shfl_xor(sa, 8);
        sb += __shfl_xor(sb, 1); sb += __shfl_xor(sb, 2);
        sb += __shfl_xor(sb, 4); sb += __shfl_xor(sb, 8);
        sc += __shfl_xor(sc, 1); sc += __shfl_xor(sc, 2);
        sc += __shfl_xor(sc, 4); sc += __shfl_xor(sc, 8);
        sd += __shfl_xor(sd, 1); sd += __shfl_xor(sd, 2);
        sd += __shfl_xor(sd, 4); sd += __shfl_xor(sd, 8);
        if (c16 == 0) {
            if (va_) tmp[ja] = sa + bb;
            if (vb_) tmp[jb] = sb + bb;
            if (vc_) tmp[jc] = sc + bb;
            if (vd_) tmp[jd] = sd + bb;
        }
    }
}

// ---- final permute: out[e] = tmp[pos[e]] (coalesced writes, cached reads) -
__global__ void k_perm(const float* __restrict__ tmp, const int* __restrict__ pos,
                       float* __restrict__ out, int E) {
    int e = blockIdx.x * blockDim.x + threadIdx.x;
    if (e < E) out[e] = tmp[pos[e]];
}

extern "C" void kernel_launch(void* const* d_in, const int* in_sizes, int n_in,
                              void* d_out, int out_size, void* d_ws, size_t ws_size,
                              hipStream_t stream) {
    const float* x  = (const float*)d_in[0];
    const int*   ei = (const int*)d_in[1];
    const float* W1 = (const float*)d_in[2];
    const float* b1 = (const float*)d_in[3];
    const float* W2 = (const float*)d_in[4];
    const float* b2 = (const float*)d_in[5];
    const float* W3 = (const float*)d_in[6];
    const float* b3 = (const float*)d_in[7];
    const float* W4 = (const float*)d_in[8];
    const float* b4 = (const float*)d_in[9];
    int N = in_sizes[0] / 3;
    int E = in_sizes[1] / 2;
    const int* row = ei;
    const int* col = ei + E;
    float* out = (float*)d_out;

    char* ws = (char*)d_ws;
    size_t off_b = 0;
    auto alloc = [&](size_t bytes) {
        void* p = ws + off_b;
        off_b += (bytes + 255) & ~(size_t)255;
        return p;
    };
    float* dinv    = (float*)alloc((size_t)N * 4);
    int*   offs    = (int*)alloc((size_t)(N + 1) * 4);
    int*   bsum    = (int*)alloc(512 * 4);
    float* bufA    = (float*)alloc((size_t)N * 64 * 4);   // ints; g2; u
    float* bufB    = (float*)alloc((size_t)N * 64 * 4);   // y4+rank; h2/v
    int*   rowlist = (int*)alloc((size_t)E * 4);
    int*   pos     = (int*)alloc((size_t)E * 4);
    float* tmp     = (float*)alloc((size_t)E * 4);

    // aliases into bufA (dead before k_layer12 writes g2=bufA):
    int* part = (int*)bufA;
    int* deg  = (int*)bufA + N;
    // aliases into bufB: y4 in first 4N floats, rank behind it
    // (both dead before k_gather writes h2=bufB).
    float4* y4  = (float4*)bufB;
    int*   rank = (int*)bufB + (size_t)4 * N;

    dim3 B(256);
    int nbN     = (N + 255) / 256;
    int nbE     = (E + 255) / 256;
    int nbNode4 = (N + 3) / 4;

    // --- CSR build (atomics only in hist) + normalization ---
    (void)hipMemsetAsync(deg, 0, (size_t)N * 4, stream);
    k_histr<<<nbE, B, 0, stream>>>(col, deg, rank, E);
    k_scan1<<<nbN, B, 0, stream>>>(deg, part, bsum, N);
    k_scan2<<<1, 512, 0, stream>>>(bsum, nbN);
    k_scan3d<<<nbN, B, 0, stream>>>(part, bsum, deg, x, offs, dinv, y4, N, E);
    k_pos<<<nbE, B, 0, stream>>>(col, rank, offs, pos, E);
    k_fillr<<<2048, B, 0, stream>>>(row, pos, rowlist, E);

    // --- fused layer1 + lin2: writes g2=bufA ---
    k_layer12<<<nbNode4, B, 0, stream>>>(y4, offs, rowlist, dinv, W1, b1, W2, bufA, N);
    // --- layer 2 aggregate: h2=bufB (LDS-free, high occupancy) ---
    k_gather<<<nbNode4, B, 0, stream>>>(bufA, offs, rowlist, dinv, b2, bufB, N);
    // --- edge MLP precompute: u=bufA (over dead g2), v in place over h2 ---
    k_lin3<<<nbNode4, B, 0, stream>>>(bufB, W3, b3, bufA, N);
    // --- edge scorer to tmp (CSR order), then permute to edge order ---
    k_edge_csr<<<nbNode4, B, 0, stream>>>((const float4*)bufA, (const float4*)bufB,
                                          offs, rowlist, (const float4*)W4, b4, tmp, N);
    k_perm<<<nbE, B, 0, stream>>>(tmp, pos, out, E);
}